// Round 17
// baseline (235.144 us; speedup 1.0000x reference)
//
#include <hip/hip_runtime.h>

#define N_NODES 50000
#define N_EDGES 600000
#define N_REL 8
#define NT_PAD 50176      // 196 * 256
#define N_TILES 196

typedef __attribute__((ext_vector_type(8))) short bf16x8;
typedef __attribute__((ext_vector_type(4))) float f32x4;

__device__ __forceinline__ ushort f2b(float f) {
    union { float f; unsigned u; } v; v.f = f;
    unsigned r = v.u + 0x7FFFu + ((v.u >> 16) & 1u);
    return (ushort)(r >> 16);
}
__device__ __forceinline__ float b2f(ushort s) {
    union { unsigned u; float f; } v; v.u = ((unsigned)s) << 16;
    return v.f;
}
__device__ __forceinline__ float asf(unsigned u) {
    union { unsigned u; float f; } v; v.u = u;
    return v.f;
}

// ---------------- converts / weight prep ----------------

__global__ void conv_f32_bf16(const float* __restrict__ in, ushort* __restrict__ outb) {
    int i = (blockIdx.x * 256 + threadIdx.x) * 4;
    float4 f = *(const float4*)(in + i);
    ushort4 o; o.x = f2b(f.x); o.y = f2b(f.y); o.z = f2b(f.z); o.w = f2b(f.w);
    *(ushort4*)(outb + i) = o;
}

// w2t [128 cols][256 k] = W2^T
__global__ void prep_w2t(const float* __restrict__ W2, ushort* __restrict__ w2t) {
    int idx = blockIdx.x * 256 + threadIdx.x;
    if (idx < 128 * 256) {
        int c = idx >> 8, k = idx & 255;
        w2t[(size_t)c * 256 + k] = f2b(W2[k * 128 + c]);
    }
}

// wtf [256 cols][1152 k]:
//   k = j < 128:       W1_top[j][c] + sum_m Wloop[j][m] * W1[(128+m)][c]   (x coefficient, fused)
//   k = 128+kg, kg<1024: Wcomb_rel[kg][c] = sum_m Wrel[kg>>7][kg&127][m] * W1[(128+m)][c]
// bcomb[c] = b1[c] + sum_m brel[m] * W1[(128+m)][c]
// block = kg (0..1152), thread = c.  Wstack row is thread-uniform (scalar loads).
__global__ void wcomb_prep(const float* __restrict__ Wrel, const float* __restrict__ Wloop,
                           const float* __restrict__ W1, const float* __restrict__ b1,
                           const float* __restrict__ brel,
                           ushort* __restrict__ wtf, float* __restrict__ bcomb) {
    const int kg = blockIdx.x;
    const int c = threadIdx.x;
    if (kg < 1024) {
        const float* wsrow = Wrel + (size_t)(kg >> 7) * 16384 + (size_t)(kg & 127) * 128;
        float acc = 0.f;
        for (int m = 0; m < 128; ++m)
            acc += wsrow[m] * W1[(128 + m) * 256 + c];
        wtf[(size_t)c * 1152 + 128 + kg] = f2b(acc);
    } else if (kg < 1152) {
        const int j = kg - 1024;
        const float* wsrow = Wloop + (size_t)j * 128;
        float acc = W1[j * 256 + c];                 // W1_top fused in
        for (int m = 0; m < 128; ++m)
            acc += wsrow[m] * W1[(128 + m) * 256 + c];
        wtf[(size_t)c * 1152 + j] = f2b(acc);
    } else {
        float acc = b1[c];
        for (int m = 0; m < 128; ++m)
            acc += brel[m] * W1[(128 + m) * 256 + c];
        bcomb[c] = acc;
    }
}

// ---------------- MFMA GEMM: 64x128 block tile, 4 waves (2x2), wave tile 32x64, BK=64 ----------------
// Double-buffered B panel (128 x 64, pad 72 shorts) + one-phase-ahead A prefetch.
// KMODE 0 (fused, NPH=18): p<2 reads A0 + p*64 (stride 128 = xbf, the x-part);
//                          p>=2 reads A1 + (p-2)*64 (stride 1024 = agg; max offset 960+63 = 1023, in-bounds).
// KMODE 2: A0 + p*64, stride AS.
// OMODE 0: f32 out+bias, width CTOT. OMODE 2: bf16 relu(out+bias), width CTOT, colbase=y*128.
template<int NPH, int KMODE, int AS, int CTOT, int OMODE>
__global__ __launch_bounds__(256, 4) void mfma_gemm(
        const ushort* __restrict__ A0, const ushort* __restrict__ A1,
        const ushort* __restrict__ Bt, const float* __restrict__ bias,
        void* __restrict__ outv) {
    __shared__ ushort bs[2][128 * 72];
    const int t = threadIdx.x;
    const int wave = t >> 6, lane = t & 63;
    const int lr = lane & 15, lg = lane >> 4;
    const int wr = (wave >> 1) * 32, wc = (wave & 1) * 64;
    const int row0 = blockIdx.x * 64;
    const int KTOT = NPH * 64;
    const ushort* Btb = Bt + (size_t)blockIdx.y * 128 * KTOT;
    const int sgk = (t & 7) * 8;
    const int sc0 = t >> 3;

#define STAGE_LOAD(p)                                                              \
    _Pragma("unroll")                                                              \
    for (int it = 0; it < 4; ++it)                                                 \
        sreg[it] = *(const bf16x8*)(Btb + (size_t)(sc0 + it * 32) * KTOT +         \
                                    (p) * 64 + sgk);

#define STAGE_WRITE(b)                                                             \
    _Pragma("unroll")                                                              \
    for (int it = 0; it < 4; ++it)                                                 \
        *(bf16x8*)(&bs[b][(sc0 + it * 32) * 72 + sgk]) = sreg[it];

#define LOAD_AF(p, dstf)                                                           \
    {                                                                              \
        const ushort* Ap; int as_;                                                 \
        if (KMODE == 0) {                                                          \
            if ((p) < 2) { Ap = A0 + (p) * 64;       as_ = 128;  }                 \
            else         { Ap = A1 + ((p) - 2) * 64; as_ = 1024; }                 \
        } else { Ap = A0 + (p) * 64; as_ = AS; }                                   \
        _Pragma("unroll")                                                          \
        for (int rt = 0; rt < 2; ++rt) {                                           \
            int ar = row0 + wr + rt * 16 + lr;                                     \
            if (ar >= N_NODES) ar = 0;                                             \
            _Pragma("unroll")                                                      \
            for (int kc = 0; kc < 2; ++kc)                                         \
                dstf[rt][kc] = *(const bf16x8*)(Ap + (size_t)ar * as_ + kc * 32 + lg * 8); \
        }                                                                          \
    }

    f32x4 acc[2][4];
#pragma unroll
    for (int rt = 0; rt < 2; ++rt)
#pragma unroll
        for (int nt = 0; nt < 4; ++nt) acc[rt][nt] = (f32x4){0.f, 0.f, 0.f, 0.f};

    bf16x8 af[2][2], afn[2][2], sreg[4];

    STAGE_LOAD(0);
    LOAD_AF(0, af);
    STAGE_WRITE(0);
    __syncthreads();

#pragma unroll
    for (int p = 0; p < NPH; ++p) {
        if (p + 1 < NPH) {
            STAGE_LOAD(p + 1);       // next B panel + next A fragments in flight
            LOAD_AF(p + 1, afn);
        }
        const ushort* bcur = bs[p & 1];
#pragma unroll
        for (int kc = 0; kc < 2; ++kc) {
            bf16x8 bf[4];
#pragma unroll
            for (int nt = 0; nt < 4; ++nt)
                bf[nt] = *(const bf16x8*)(bcur + (wc + nt * 16 + lr) * 72 + kc * 32 + lg * 8);
#pragma unroll
            for (int rt = 0; rt < 2; ++rt)
#pragma unroll
                for (int nt = 0; nt < 4; ++nt)
                    acc[rt][nt] = __builtin_amdgcn_mfma_f32_16x16x32_bf16(af[rt][kc], bf[nt], acc[rt][nt], 0, 0, 0);
        }
        if (p + 1 < NPH) STAGE_WRITE((p + 1) & 1);  // write-late, after compute
        __syncthreads();
        if (p + 1 < NPH) {
#pragma unroll
            for (int rt = 0; rt < 2; ++rt)
#pragma unroll
                for (int kc = 0; kc < 2; ++kc) af[rt][kc] = afn[rt][kc];
        }
    }

    const int colbase = blockIdx.y * 128;
#pragma unroll
    for (int rt = 0; rt < 2; ++rt) {
#pragma unroll
        for (int nt = 0; nt < 4; ++nt) {
            const int col = colbase + wc + nt * 16 + lr;
            const float bv = bias[col];
#pragma unroll
            for (int j = 0; j < 4; ++j) {
                const int r = row0 + wr + rt * 16 + lg * 4 + j;
                if (r >= N_NODES) continue;
                float vv = acc[rt][nt][j] + bv;
                if (OMODE == 0) {
                    ((float*)outv)[(size_t)r * CTOT + col] = vv;
                } else { // OMODE 2
                    ((ushort*)outv)[(size_t)r * CTOT + col] = f2b(fmaxf(vv, 0.f));
                }
            }
        }
    }
#undef STAGE_LOAD
#undef STAGE_WRITE
#undef LOAD_AF
}

// ---------------- CSR build (counting sort by dst) ----------------

__global__ void zero_cnt(int* __restrict__ cnt) {
    int i = blockIdx.x * 256 + threadIdx.x;
    if (i < NT_PAD) cnt[i] = 0;
}

__global__ void hist_dst(const int* __restrict__ dst, int* __restrict__ cnt) {
    int e = blockIdx.x * 256 + threadIdx.x;
    if (e < N_EDGES) atomicAdd(&cnt[dst[e]], 1);
}

__global__ void scan_tiles(const int* __restrict__ cnt, int* __restrict__ tincl, int* __restrict__ bsum) {
    __shared__ int s[256];
    int i = blockIdx.x * 256 + threadIdx.x;
    int v = cnt[i];
    s[threadIdx.x] = v;
    __syncthreads();
    for (int off = 1; off < 256; off <<= 1) {
        int add = (threadIdx.x >= off) ? s[threadIdx.x - off] : 0;
        __syncthreads();
        s[threadIdx.x] += add;
        __syncthreads();
    }
    tincl[i] = s[threadIdx.x];
    if (threadIdx.x == 255) bsum[blockIdx.x] = s[255];
}

__global__ void scan_bsum(const int* __restrict__ bsum, int* __restrict__ bex) {
    __shared__ int s[256];
    int v = (threadIdx.x < N_TILES) ? bsum[threadIdx.x] : 0;
    s[threadIdx.x] = v;
    __syncthreads();
    for (int off = 1; off < 256; off <<= 1) {
        int add = (threadIdx.x >= off) ? s[threadIdx.x - off] : 0;
        __syncthreads();
        s[threadIdx.x] += add;
        __syncthreads();
    }
    if (threadIdx.x < N_TILES) bex[threadIdx.x] = s[threadIdx.x] - v;
}

__global__ void finalize_base(const int* __restrict__ cnt, const int* __restrict__ tincl,
                              const int* __restrict__ bex, int* __restrict__ base,
                              int* __restrict__ cursor) {
    int i = blockIdx.x * 256 + threadIdx.x;
    int b = tincl[i] - cnt[i] + bex[blockIdx.x];
    base[i] = b; cursor[i] = b;
}

__global__ void scatter_ids(const int* __restrict__ src, const int* __restrict__ dst,
                            const int* __restrict__ et, int* __restrict__ cursor,
                            unsigned* __restrict__ sorted) {
    int e = blockIdx.x * 256 + threadIdx.x;
    if (e >= N_EDGES) return;
    int pos = atomicAdd(&cursor[dst[e]], 1);
    sorted[pos] = ((unsigned)src[e] << 3) | (unsigned)et[e];
}

// ---------------- gather_agg (r14 proven: scalar bases + real branch chain) ----------------

#define ACC_ADD(sd, v)                                                       \
    {                                                                        \
        float lo = asf((v) << 16);                                           \
        float hi = asf((v) & 0xffff0000u);                                   \
        switch ((sd) & 7u) {                                                 \
            case 0: a0[0] += lo; a1[0] += hi; asm volatile(""); break;       \
            case 1: a0[1] += lo; a1[1] += hi; asm volatile(""); break;       \
            case 2: a0[2] += lo; a1[2] += hi; asm volatile(""); break;       \
            case 3: a0[3] += lo; a1[3] += hi; asm volatile(""); break;       \
            case 4: a0[4] += lo; a1[4] += hi; asm volatile(""); break;       \
            case 5: a0[5] += lo; a1[5] += hi; asm volatile(""); break;       \
            case 6: a0[6] += lo; a1[6] += hi; asm volatile(""); break;       \
            default: a0[7] += lo; a1[7] += hi; asm volatile(""); break;      \
        }                                                                    \
    }

__global__ __launch_bounds__(256) void gather_agg(
        const unsigned* __restrict__ sorted, const int* __restrict__ base,
        const int* __restrict__ cnt, const ushort* __restrict__ xbf,
        ushort* __restrict__ agg) {
    const int w = threadIdx.x >> 6, lane = threadIdx.x & 63;
    const int n = blockIdx.x * 4 + w;
    const int b = base[n], c = cnt[n];
    const int loff = lane * 2;

    float a0[8], a1[8];
#pragma unroll
    for (int r = 0; r < 8; ++r) { a0[r] = 0.f; a1[r] = 0.f; }

    const unsigned* sp = sorted + b;
    int i = 0;
    for (; i + 4 <= c; i += 4) {
        unsigned s0 = __builtin_amdgcn_readfirstlane(sp[i]);
        unsigned s1 = __builtin_amdgcn_readfirstlane(sp[i + 1]);
        unsigned s2 = __builtin_amdgcn_readfirstlane(sp[i + 2]);
        unsigned s3 = __builtin_amdgcn_readfirstlane(sp[i + 3]);
        unsigned v0 = *(const unsigned*)(xbf + ((size_t)(s0 >> 3) << 7) + loff);
        unsigned v1 = *(const unsigned*)(xbf + ((size_t)(s1 >> 3) << 7) + loff);
        unsigned v2 = *(const unsigned*)(xbf + ((size_t)(s2 >> 3) << 7) + loff);
        unsigned v3 = *(const unsigned*)(xbf + ((size_t)(s3 >> 3) << 7) + loff);
        ACC_ADD(s0, v0); ACC_ADD(s1, v1); ACC_ADD(s2, v2); ACC_ADD(s3, v3);
    }
    for (; i < c; ++i) {
        unsigned sd = __builtin_amdgcn_readfirstlane(sp[i]);
        unsigned v = *(const unsigned*)(xbf + ((size_t)(sd >> 3) << 7) + loff);
        ACC_ADD(sd, v);
    }
#pragma unroll
    for (int r = 0; r < 8; ++r) {
        unsigned pk = (unsigned)f2b(a0[r]) | ((unsigned)f2b(a1[r]) << 16);
        *(unsigned*)(agg + (size_t)n * 1024 + r * 128 + loff) = pk;
    }
}
#undef ACC_ADD

// ---------------- launch ----------------

extern "C" void kernel_launch(void* const* d_in, const int* in_sizes, int n_in,
                              void* d_out, int out_size, void* d_ws, size_t ws_size,
                              hipStream_t stream) {
    const float* x     = (const float*)d_in[0];
    const int*   src   = (const int*)  d_in[1];
    const int*   dst   = (const int*)  d_in[2];
    const int*   etype = (const int*)  d_in[3];
    const float* Wrel  = (const float*)d_in[4];
    const float* Wloop = (const float*)d_in[5];
    const float* brel  = (const float*)d_in[6];
    const float* W1    = (const float*)d_in[7];
    const float* b1    = (const float*)d_in[8];
    const float* W2    = (const float*)d_in[9];
    const float* b2    = (const float*)d_in[10];
    float* out = (float*)d_out;

    // ws layout — total 144,661,248 B (ws_size = 256 MiB, confirmed round 7/8).
    char* ws = (char*)d_ws;
    ushort* agg   = (ushort*)ws;                     // 102,400,000 B  [N][1024] bf16
    ushort* wtf   = (ushort*)(ws + 102400000);       //     589,824 B  [256][1152]: (W1_top + Wcomb_loop)^T | Wcomb_rel^T
    ushort* w2t   = (ushort*)(ws + 102989824);       //      65,536 B  [128][256] = W2^T
    float*  bcomb = (float*) (ws + 103055360);       //       1,024 B
    char* meta    = ws + 103056384;
    int* cnt      = (int*)(meta);                    // 200,704 B
    int* base     = (int*)(meta + 200704);           // 200,704 B
    int* cursor   = (int*)(meta + 401408);           // 200,704 B
    int* tincl    = (int*)(meta + 602112);           // 200,704 B
    int* bsum     = (int*)(meta + 802816);           //   1,024 B
    int* bex      = (int*)(meta + 803840);           //   1,024 B
    unsigned* sorted = (unsigned*)(meta + 804864);   // 2,400,000 B  (meta end 106,261,248)
    ushort* xbf   = (ushort*)(ws + 106261248);       // 12,800,000 B  bf16(x)
    ushort* h     = (ushort*)(ws + 119061248);       // 25,600,000 B  [N][256] bf16  (end 144,661,248)

    conv_f32_bf16<<<6250, 256, 0, stream>>>(x, xbf);
    prep_w2t<<<128, 256, 0, stream>>>(W2, w2t);
    // wtf cols 0..127 = W1_top + Wloop@W1_bot; cols 128..1151 = Wrel-stack @ W1_bot; bcomb
    wcomb_prep<<<1153, 256, 0, stream>>>(Wrel, Wloop, W1, b1, brel, wtf, bcomb);

    // CSR build (counting sort of edges by dst)
    zero_cnt<<<N_TILES, 256, 0, stream>>>(cnt);
    hist_dst<<<(N_EDGES + 255) / 256, 256, 0, stream>>>(dst, cnt);
    scan_tiles<<<N_TILES, 256, 0, stream>>>(cnt, tincl, bsum);
    scan_bsum<<<1, 256, 0, stream>>>(bsum, bex);
    finalize_base<<<N_TILES, 256, 0, stream>>>(cnt, tincl, bex, base, cursor);
    scatter_ids<<<(N_EDGES + 255) / 256, 256, 0, stream>>>(src, dst, etype, cursor, sorted);

    // agg[n][r] = sum of x[src] over edges (dst=n, etype=r)
    gather_agg<<<N_NODES / 4, 256, 0, stream>>>(sorted, base, cnt, xbf, agg);

    // h = relu( x @ (W1_top + Wloop@W1_bot) + agg @ Wcomb_rel + bcomb )   (K = 1152, 18 phases)
    mfma_gemm<18, 0, 0, 256, 2><<<dim3(782, 2), 256, 0, stream>>>(xbf, agg, wtf, bcomb, (void*)h);

    // out = h @ W2 + b2  (f32)  (K = 256, 4 phases)
    mfma_gemm<4, 2, 256, 128, 0><<<dim3(782, 1), 256, 0, stream>>>(h, nullptr, w2t, b2, out);
}

// Round 18
// 207.388 us; speedup vs baseline: 1.1338x; 1.1338x over previous
//
#include <hip/hip_runtime.h>

#define N_NODES 50000
#define N_EDGES 600000
#define N_REL 8
#define NT_PAD 50176      // 196 * 256
#define N_TILES 196

typedef __attribute__((ext_vector_type(8))) short bf16x8;
typedef __attribute__((ext_vector_type(4))) float f32x4;

__device__ __forceinline__ ushort f2b(float f) {
    union { float f; unsigned u; } v; v.f = f;
    unsigned r = v.u + 0x7FFFu + ((v.u >> 16) & 1u);
    return (ushort)(r >> 16);
}
__device__ __forceinline__ float b2f(ushort s) {
    union { unsigned u; float f; } v; v.u = ((unsigned)s) << 16;
    return v.f;
}
__device__ __forceinline__ float asf(unsigned u) {
    union { unsigned u; float f; } v; v.u = u;
    return v.f;
}

// ---------------- converts / weight prep ----------------

__global__ void conv_f32_bf16(const float* __restrict__ in, ushort* __restrict__ outb) {
    int i = (blockIdx.x * 256 + threadIdx.x) * 4;
    float4 f = *(const float4*)(in + i);
    ushort4 o; o.x = f2b(f.x); o.y = f2b(f.y); o.z = f2b(f.z); o.w = f2b(f.w);
    *(ushort4*)(outb + i) = o;
}

// wst [128 cols][1152 k] = stack(Wrel[0..7], Wloop)^T ; w1t [256][256]; w2t [128][256]
__global__ void transpose_wts3(const float* __restrict__ Wloop, const float* __restrict__ Wrel,
                               const float* __restrict__ W1, const float* __restrict__ W2,
                               ushort* __restrict__ wt) {
    int y = blockIdx.y;
    if (y == 0) {
        for (int idx = blockIdx.x * 256 + threadIdx.x; idx < 128 * 1152; idx += gridDim.x * 256) {
            int c = idx / 1152, kg = idx - c * 1152;
            float v = (kg < 1024) ? Wrel[(size_t)((kg >> 7) * 128 + (kg & 127)) * 128 + c]
                                  : Wloop[(size_t)(kg - 1024) * 128 + c];
            wt[idx] = f2b(v);
        }
    } else if (y == 1) {
        for (int idx = blockIdx.x * 256 + threadIdx.x; idx < 256 * 256; idx += gridDim.x * 256) {
            int c = idx >> 8, k = idx & 255;
            wt[147456 + idx] = f2b(W1[k * 256 + c]);
        }
    } else {
        for (int idx = blockIdx.x * 256 + threadIdx.x; idx < 128 * 256; idx += gridDim.x * 256) {
            int c = idx >> 8, k = idx & 255;
            wt[212992 + idx] = f2b(W2[k * 128 + c]);
        }
    }
}

// ---------------- MFMA GEMM (r15 proven): 64x128 tile, 4 waves, BK=64, dbuf + A-prefetch ----------------
// KMODE 0 (NPH=18): p<16 reads A0 + p*64 (stride 1024 = agg), p>=16 reads A1 + (p-16)*64 (stride 128).
// OMODE 4: bf16 out+bias, width 128.
template<int NPH, int KMODE, int AS, int CTOT, int OMODE>
__global__ __launch_bounds__(256, 4) void mfma_gemm(
        const ushort* __restrict__ A0, const ushort* __restrict__ A1,
        const ushort* __restrict__ Bt, const float* __restrict__ bias,
        void* __restrict__ outv) {
    __shared__ ushort bs[2][128 * 72];
    const int t = threadIdx.x;
    const int wave = t >> 6, lane = t & 63;
    const int lr = lane & 15, lg = lane >> 4;
    const int wr = (wave >> 1) * 32, wc = (wave & 1) * 64;
    const int row0 = blockIdx.x * 64;
    const int KTOT = NPH * 64;
    const ushort* Btb = Bt + (size_t)blockIdx.y * 128 * KTOT;
    const int sgk = (t & 7) * 8;
    const int sc0 = t >> 3;

#define STAGE_LOAD(p)                                                              \
    _Pragma("unroll")                                                              \
    for (int it = 0; it < 4; ++it)                                                 \
        sreg[it] = *(const bf16x8*)(Btb + (size_t)(sc0 + it * 32) * KTOT +         \
                                    (p) * 64 + sgk);

#define STAGE_WRITE(b)                                                             \
    _Pragma("unroll")                                                              \
    for (int it = 0; it < 4; ++it)                                                 \
        *(bf16x8*)(&bs[b][(sc0 + it * 32) * 72 + sgk]) = sreg[it];

#define LOAD_AF(p, dstf)                                                           \
    {                                                                              \
        const ushort* Ap; int as_;                                                 \
        if (KMODE == 0) {                                                          \
            if ((p) < 16) { Ap = A0 + (p) * 64;        as_ = 1024; }               \
            else          { Ap = A1 + ((p) - 16) * 64; as_ = 128;  }               \
        } else { Ap = A0 + (p) * 64; as_ = AS; }                                   \
        _Pragma("unroll")                                                          \
        for (int rt = 0; rt < 2; ++rt) {                                           \
            int ar = row0 + wr + rt * 16 + lr;                                     \
            if (ar >= N_NODES) ar = 0;                                             \
            _Pragma("unroll")                                                      \
            for (int kc = 0; kc < 2; ++kc)                                         \
                dstf[rt][kc] = *(const bf16x8*)(Ap + (size_t)ar * as_ + kc * 32 + lg * 8); \
        }                                                                          \
    }

    f32x4 acc[2][4];
#pragma unroll
    for (int rt = 0; rt < 2; ++rt)
#pragma unroll
        for (int nt = 0; nt < 4; ++nt) acc[rt][nt] = (f32x4){0.f, 0.f, 0.f, 0.f};

    bf16x8 af[2][2], afn[2][2], sreg[4];

    STAGE_LOAD(0);
    LOAD_AF(0, af);
    STAGE_WRITE(0);
    __syncthreads();

#pragma unroll
    for (int p = 0; p < NPH; ++p) {
        if (p + 1 < NPH) {
            STAGE_LOAD(p + 1);
            LOAD_AF(p + 1, afn);
        }
        const ushort* bcur = bs[p & 1];
#pragma unroll
        for (int kc = 0; kc < 2; ++kc) {
            bf16x8 bf[4];
#pragma unroll
            for (int nt = 0; nt < 4; ++nt)
                bf[nt] = *(const bf16x8*)(bcur + (wc + nt * 16 + lr) * 72 + kc * 32 + lg * 8);
#pragma unroll
            for (int rt = 0; rt < 2; ++rt)
#pragma unroll
                for (int nt = 0; nt < 4; ++nt)
                    acc[rt][nt] = __builtin_amdgcn_mfma_f32_16x16x32_bf16(af[rt][kc], bf[nt], acc[rt][nt], 0, 0, 0);
        }
        if (p + 1 < NPH) STAGE_WRITE((p + 1) & 1);
        __syncthreads();
        if (p + 1 < NPH) {
#pragma unroll
            for (int rt = 0; rt < 2; ++rt)
#pragma unroll
                for (int kc = 0; kc < 2; ++kc) af[rt][kc] = afn[rt][kc];
        }
    }

    const int colbase = blockIdx.y * 128;
#pragma unroll
    for (int rt = 0; rt < 2; ++rt) {
#pragma unroll
        for (int nt = 0; nt < 4; ++nt) {
            const int col = colbase + wc + nt * 16 + lr;
            const float bv = bias[col];
#pragma unroll
            for (int j = 0; j < 4; ++j) {
                const int r = row0 + wr + rt * 16 + lg * 4 + j;
                if (r >= N_NODES) continue;
                float vv = acc[rt][nt][j] + bv;
                if (OMODE == 0) {
                    ((float*)outv)[(size_t)r * CTOT + col] = vv;
                } else { // OMODE 4
                    ((ushort*)outv)[(size_t)r * 128 + col] = f2b(vv);
                }
            }
        }
    }
#undef STAGE_LOAD
#undef STAGE_WRITE
#undef LOAD_AF
}

// ---------------- fused MLP: h = relu([x|mid]@W1+b1) in LDS; out = h@W2 + b2 ----------------
// Block = 64 nodes, 256 threads. Stage 1: tile 64x256, wave tile 32x128, W1 panels dbuf.
// h bf16 -> ldsA [64][264] (stride 264 shorts: 16B-aligned, 2-way banks = free).
// Stage 2: A from ldsA, W2 panels dbuf in ldsB halves, out f32.
__global__ __launch_bounds__(256, 2) void mlp_fused(
        const ushort* __restrict__ xbf, const ushort* __restrict__ midbf,
        const ushort* __restrict__ w1t, const ushort* __restrict__ w2t,
        const float* __restrict__ b1, const float* __restrict__ b2,
        float* __restrict__ out) {
    __shared__ ushort ldsA[256 * 72];   // stage1 B buf0 (256x72); then h [64][264] (16,896 used)
    __shared__ ushort ldsB[256 * 72];   // stage1 B buf1; then stage2 B dbuf halves (2 x 128x72)
    const int t = threadIdx.x;
    const int wave = t >> 6, lane = t & 63;
    const int lr = lane & 15, lg = lane >> 4;
    const int row0 = blockIdx.x * 64;
    const int sgk = (t & 7) * 8;
    const int sc0 = t >> 3;

    // ======== stage 1 ========
    {
        const int wr = (wave >> 1) * 32, wc = (wave & 1) * 128;
        f32x4 acc[2][8];
#pragma unroll
        for (int rt = 0; rt < 2; ++rt)
#pragma unroll
            for (int nt = 0; nt < 8; ++nt) acc[rt][nt] = (f32x4){0.f, 0.f, 0.f, 0.f};
        bf16x8 af[2][2], afn[2][2], sreg[8];

#define S1_LOAD(p)                                                                 \
    _Pragma("unroll")                                                              \
    for (int it = 0; it < 8; ++it)                                                 \
        sreg[it] = *(const bf16x8*)(w1t + (size_t)(sc0 + it * 32) * 256 + (p) * 64 + sgk);

#define S1_WRITE(bptr)                                                             \
    _Pragma("unroll")                                                              \
    for (int it = 0; it < 8; ++it)                                                 \
        *(bf16x8*)((bptr) + (sc0 + it * 32) * 72 + sgk) = sreg[it];

#define S1_AF(p, dstf)                                                             \
    {                                                                              \
        const ushort* Ap = ((p) < 2) ? (xbf + (p) * 64) : (midbf + ((p) - 2) * 64);\
        _Pragma("unroll")                                                          \
        for (int rt = 0; rt < 2; ++rt) {                                           \
            int ar = row0 + wr + rt * 16 + lr;                                     \
            if (ar >= N_NODES) ar = 0;                                             \
            _Pragma("unroll")                                                      \
            for (int kc = 0; kc < 2; ++kc)                                         \
                dstf[rt][kc] = *(const bf16x8*)(Ap + (size_t)ar * 128 + kc * 32 + lg * 8); \
        }                                                                          \
    }

        S1_LOAD(0); S1_AF(0, af); S1_WRITE(ldsA);
        __syncthreads();
#pragma unroll
        for (int p = 0; p < 4; ++p) {
            if (p < 3) { S1_LOAD(p + 1); S1_AF(p + 1, afn); }
            const ushort* bc = (p & 1) ? ldsB : ldsA;
#pragma unroll
            for (int kc = 0; kc < 2; ++kc) {
                bf16x8 bf[8];
#pragma unroll
                for (int nt = 0; nt < 8; ++nt)
                    bf[nt] = *(const bf16x8*)(bc + (wc + nt * 16 + lr) * 72 + kc * 32 + lg * 8);
#pragma unroll
                for (int rt = 0; rt < 2; ++rt)
#pragma unroll
                    for (int nt = 0; nt < 8; ++nt)
                        acc[rt][nt] = __builtin_amdgcn_mfma_f32_16x16x32_bf16(af[rt][kc], bf[nt], acc[rt][nt], 0, 0, 0);
            }
            if (p < 3) { S1_WRITE(((p + 1) & 1) ? ldsB : ldsA); }
            __syncthreads();
            if (p < 3) {
#pragma unroll
                for (int rt = 0; rt < 2; ++rt)
#pragma unroll
                    for (int kc = 0; kc < 2; ++kc) af[rt][kc] = afn[rt][kc];
            }
        }
        // write h = relu(acc + b1) as bf16 into ldsA [64][264]
        // (safe: last ldsA panel-read was phase 2, its end-of-phase barrier passed;
        //  each wave writes a disjoint (row,col) region)
#pragma unroll
        for (int rt = 0; rt < 2; ++rt)
#pragma unroll
            for (int nt = 0; nt < 8; ++nt) {
                const int col = wc + nt * 16 + lr;
                const float bv = b1[col];
#pragma unroll
                for (int j = 0; j < 4; ++j) {
                    const int hr = wr + rt * 16 + lg * 4 + j;
                    ldsA[hr * 264 + col] = f2b(fmaxf(acc[rt][nt][j] + bv, 0.f));
                }
            }
#undef S1_LOAD
#undef S1_WRITE
#undef S1_AF
    }

    // ======== stage 2 ========
    {
        bf16x8 sreg2[4];
#define S2_LOAD(p)                                                                 \
    _Pragma("unroll")                                                              \
    for (int it = 0; it < 4; ++it)                                                 \
        sreg2[it] = *(const bf16x8*)(w2t + (size_t)(sc0 + it * 32) * 256 + (p) * 64 + sgk);

#define S2_WRITE(half)                                                             \
    _Pragma("unroll")                                                              \
    for (int it = 0; it < 4; ++it)                                                 \
        *(bf16x8*)(ldsB + (half) * (128 * 72) + (sc0 + it * 32) * 72 + sgk) = sreg2[it];

        S2_LOAD(0); S2_WRITE(0);
        __syncthreads();   // h visible to all waves + W2 panel 0 staged

        const int wr = (wave >> 1) * 32, wc = (wave & 1) * 64;
        f32x4 acc[2][4];
#pragma unroll
        for (int rt = 0; rt < 2; ++rt)
#pragma unroll
            for (int nt = 0; nt < 4; ++nt) acc[rt][nt] = (f32x4){0.f, 0.f, 0.f, 0.f};
        bf16x8 af[2][2];

#pragma unroll
        for (int p = 0; p < 4; ++p) {
            if (p < 3) S2_LOAD(p + 1);
            // A-fragments from h in LDS (stride 264: 2-way banks, free)
#pragma unroll
            for (int rt = 0; rt < 2; ++rt) {
                const int ar = wr + rt * 16 + lr;
#pragma unroll
                for (int kc = 0; kc < 2; ++kc)
                    af[rt][kc] = *(const bf16x8*)(ldsA + ar * 264 + p * 64 + kc * 32 + lg * 8);
            }
            const ushort* bc = ldsB + (p & 1) * (128 * 72);
#pragma unroll
            for (int kc = 0; kc < 2; ++kc) {
                bf16x8 bf[4];
#pragma unroll
                for (int nt = 0; nt < 4; ++nt)
                    bf[nt] = *(const bf16x8*)(bc + (wc + nt * 16 + lr) * 72 + kc * 32 + lg * 8);
#pragma unroll
                for (int rt = 0; rt < 2; ++rt)
#pragma unroll
                    for (int nt = 0; nt < 4; ++nt)
                        acc[rt][nt] = __builtin_amdgcn_mfma_f32_16x16x32_bf16(af[rt][kc], bf[nt], acc[rt][nt], 0, 0, 0);
            }
            if (p < 3) S2_WRITE((p + 1) & 1);
            __syncthreads();
        }
#pragma unroll
        for (int rt = 0; rt < 2; ++rt)
#pragma unroll
            for (int nt = 0; nt < 4; ++nt) {
                const int col = wc + nt * 16 + lr;
                const float bv = b2[col];
#pragma unroll
                for (int j = 0; j < 4; ++j) {
                    const int r = row0 + wr + rt * 16 + lg * 4 + j;
                    if (r < N_NODES)
                        out[(size_t)r * 128 + col] = acc[rt][nt][j] + bv;
                }
            }
#undef S2_LOAD
#undef S2_WRITE
    }
}

// ---------------- CSR build (counting sort by dst) ----------------

__global__ void zero_cnt(int* __restrict__ cnt) {
    int i = blockIdx.x * 256 + threadIdx.x;
    if (i < NT_PAD) cnt[i] = 0;
}

__global__ void hist_dst(const int* __restrict__ dst, int* __restrict__ cnt) {
    int e = blockIdx.x * 256 + threadIdx.x;
    if (e < N_EDGES) atomicAdd(&cnt[dst[e]], 1);
}

__global__ void scan_tiles(const int* __restrict__ cnt, int* __restrict__ tincl, int* __restrict__ bsum) {
    __shared__ int s[256];
    int i = blockIdx.x * 256 + threadIdx.x;
    int v = cnt[i];
    s[threadIdx.x] = v;
    __syncthreads();
    for (int off = 1; off < 256; off <<= 1) {
        int add = (threadIdx.x >= off) ? s[threadIdx.x - off] : 0;
        __syncthreads();
        s[threadIdx.x] += add;
        __syncthreads();
    }
    tincl[i] = s[threadIdx.x];
    if (threadIdx.x == 255) bsum[blockIdx.x] = s[255];
}

__global__ void scan_bsum(const int* __restrict__ bsum, int* __restrict__ bex) {
    __shared__ int s[256];
    int v = (threadIdx.x < N_TILES) ? bsum[threadIdx.x] : 0;
    s[threadIdx.x] = v;
    __syncthreads();
    for (int off = 1; off < 256; off <<= 1) {
        int add = (threadIdx.x >= off) ? s[threadIdx.x - off] : 0;
        __syncthreads();
        s[threadIdx.x] += add;
        __syncthreads();
    }
    if (threadIdx.x < N_TILES) bex[threadIdx.x] = s[threadIdx.x] - v;
}

__global__ void finalize_base(const int* __restrict__ cnt, const int* __restrict__ tincl,
                              const int* __restrict__ bex, int* __restrict__ base,
                              int* __restrict__ cursor) {
    int i = blockIdx.x * 256 + threadIdx.x;
    int b = tincl[i] - cnt[i] + bex[blockIdx.x];
    base[i] = b; cursor[i] = b;
}

__global__ void scatter_ids(const int* __restrict__ src, const int* __restrict__ dst,
                            const int* __restrict__ et, int* __restrict__ cursor,
                            unsigned* __restrict__ sorted) {
    int e = blockIdx.x * 256 + threadIdx.x;
    if (e >= N_EDGES) return;
    int pos = atomicAdd(&cursor[dst[e]], 1);
    sorted[pos] = ((unsigned)src[e] << 3) | (unsigned)et[e];
}

// ---------------- gather_agg (r14 proven: scalar bases + real branch chain) ----------------

#define ACC_ADD(sd, v)                                                       \
    {                                                                        \
        float lo = asf((v) << 16);                                           \
        float hi = asf((v) & 0xffff0000u);                                   \
        switch ((sd) & 7u) {                                                 \
            case 0: a0[0] += lo; a1[0] += hi; asm volatile(""); break;       \
            case 1: a0[1] += lo; a1[1] += hi; asm volatile(""); break;       \
            case 2: a0[2] += lo; a1[2] += hi; asm volatile(""); break;       \
            case 3: a0[3] += lo; a1[3] += hi; asm volatile(""); break;       \
            case 4: a0[4] += lo; a1[4] += hi; asm volatile(""); break;       \
            case 5: a0[5] += lo; a1[5] += hi; asm volatile(""); break;       \
            case 6: a0[6] += lo; a1[6] += hi; asm volatile(""); break;       \
            default: a0[7] += lo; a1[7] += hi; asm volatile(""); break;      \
        }                                                                    \
    }

__global__ __launch_bounds__(256) void gather_agg(
        const unsigned* __restrict__ sorted, const int* __restrict__ base,
        const int* __restrict__ cnt, const ushort* __restrict__ xbf,
        ushort* __restrict__ agg) {
    const int w = threadIdx.x >> 6, lane = threadIdx.x & 63;
    const int n = blockIdx.x * 4 + w;
    const int b = base[n], c = cnt[n];
    const int loff = lane * 2;

    float a0[8], a1[8];
#pragma unroll
    for (int r = 0; r < 8; ++r) { a0[r] = 0.f; a1[r] = 0.f; }

    const unsigned* sp = sorted + b;
    int i = 0;
    for (; i + 4 <= c; i += 4) {
        unsigned s0 = __builtin_amdgcn_readfirstlane(sp[i]);
        unsigned s1 = __builtin_amdgcn_readfirstlane(sp[i + 1]);
        unsigned s2 = __builtin_amdgcn_readfirstlane(sp[i + 2]);
        unsigned s3 = __builtin_amdgcn_readfirstlane(sp[i + 3]);
        unsigned v0 = *(const unsigned*)(xbf + ((size_t)(s0 >> 3) << 7) + loff);
        unsigned v1 = *(const unsigned*)(xbf + ((size_t)(s1 >> 3) << 7) + loff);
        unsigned v2 = *(const unsigned*)(xbf + ((size_t)(s2 >> 3) << 7) + loff);
        unsigned v3 = *(const unsigned*)(xbf + ((size_t)(s3 >> 3) << 7) + loff);
        ACC_ADD(s0, v0); ACC_ADD(s1, v1); ACC_ADD(s2, v2); ACC_ADD(s3, v3);
    }
    for (; i < c; ++i) {
        unsigned sd = __builtin_amdgcn_readfirstlane(sp[i]);
        unsigned v = *(const unsigned*)(xbf + ((size_t)(sd >> 3) << 7) + loff);
        ACC_ADD(sd, v);
    }
#pragma unroll
    for (int r = 0; r < 8; ++r) {
        unsigned pk = (unsigned)f2b(a0[r]) | ((unsigned)f2b(a1[r]) << 16);
        *(unsigned*)(agg + (size_t)n * 1024 + r * 128 + loff) = pk;
    }
}
#undef ACC_ADD

// ---------------- launch ----------------

extern "C" void kernel_launch(void* const* d_in, const int* in_sizes, int n_in,
                              void* d_out, int out_size, void* d_ws, size_t ws_size,
                              hipStream_t stream) {
    const float* x     = (const float*)d_in[0];
    const int*   src   = (const int*)  d_in[1];
    const int*   dst   = (const int*)  d_in[2];
    const int*   etype = (const int*)  d_in[3];
    const float* Wrel  = (const float*)d_in[4];
    const float* Wloop = (const float*)d_in[5];
    const float* brel  = (const float*)d_in[6];
    const float* W1    = (const float*)d_in[7];
    const float* b1    = (const float*)d_in[8];
    const float* W2    = (const float*)d_in[9];
    const float* b2    = (const float*)d_in[10];
    float* out = (float*)d_out;

    // ws layout — total 131,696,384 B (ws_size = 256 MiB, confirmed round 7/8).
    char* ws = (char*)d_ws;
    ushort* agg   = (ushort*)ws;                     // 102,400,000 B  [N][1024] bf16
    ushort* wt    = (ushort*)(ws + 102400000);       //     491,520 B  wst/w1t/w2t
    char* meta    = ws + 102891520;
    int* cnt      = (int*)(meta);                    // 200,704 B
    int* base     = (int*)(meta + 200704);           // 200,704 B
    int* cursor   = (int*)(meta + 401408);           // 200,704 B
    int* tincl    = (int*)(meta + 602112);           // 200,704 B
    int* bsum     = (int*)(meta + 802816);           //   1,024 B
    int* bex      = (int*)(meta + 803840);           //   1,024 B
    unsigned* sorted = (unsigned*)(meta + 804864);   // 2,400,000 B  (meta end 106,096,384)
    ushort* xbf   = (ushort*)(ws + 106096384);       // 12,800,000 B  bf16(x)
    ushort* midbf = (ushort*)(ws + 118896384);       // 12,800,000 B  bf16(mid)  (end 131,696,384)

    const ushort* wst = wt;              // [128][1152]  stack(Wrel, Wloop)^T
    const ushort* w1t = wt + 147456;     // [256][256]
    const ushort* w2t = wt + 212992;     // [128][256]

    conv_f32_bf16<<<6250, 256, 0, stream>>>(x, xbf);
    transpose_wts3<<<dim3(64, 3), 256, 0, stream>>>(Wloop, Wrel, W1, W2, wt);

    // CSR build (counting sort of edges by dst)
    zero_cnt<<<N_TILES, 256, 0, stream>>>(cnt);
    hist_dst<<<(N_EDGES + 255) / 256, 256, 0, stream>>>(dst, cnt);
    scan_tiles<<<N_TILES, 256, 0, stream>>>(cnt, tincl, bsum);
    scan_bsum<<<1, 256, 0, stream>>>(bsum, bex);
    finalize_base<<<N_TILES, 256, 0, stream>>>(cnt, tincl, bex, base, cursor);
    scatter_ids<<<(N_EDGES + 255) / 256, 256, 0, stream>>>(src, dst, etype, cursor, sorted);

    // agg[n][r] = sum of x[src] over edges (dst=n, etype=r)
    gather_agg<<<N_NODES / 4, 256, 0, stream>>>(sorted, base, cnt, xbf, agg);

    // midbf = bf16( concat(agg_0..7, x) @ stack(Wrel, Wloop) + brel )   (K = 1152, 18 phases)
    mfma_gemm<18, 0, 0, 128, 4><<<dim3(782, 1), 256, 0, stream>>>(agg, xbf, wst, brel, (void*)midbf);

    // out = relu(concat(x, mid) @ W1 + b1) @ W2 + b2   (fused, h in LDS)
    mlp_fused<<<782, 256, 0, stream>>>(xbf, midbf, w1t, w2t, b1, b2, out);
}